// Round 1
// baseline (836.529 us; speedup 1.0000x reference)
//
#include <hip/hip_runtime.h>
#include <math.h>

// VanillaRNN: B=1024, T=512, I=64, H=128, O=10, fp32.
// One block per batch element (recurrence independent across B -> no grid sync).
// 256 threads: output j = tid&127, half = tid>>7 (wave-uniform).
// Weights held in registers (96 floats/thread); operand vector [h | x_t] in LDS,
// read at wave-uniform addresses -> broadcast, conflict-free, b128-vectorizable.

#define T_STEPS 512
#define I_DIM   64
#define H_DIM   128
#define O_DIM   10
#define KTOT    192   // H + I
#define WPT     96    // weights per thread = KTOT/2

__global__ __launch_bounds__(256) void rnn_fused_kernel(
    const float* __restrict__ x,      // [B, T, I]
    const float* __restrict__ W_hx,   // [H, I]
    const float* __restrict__ W_hh,   // [H, H]
    const float* __restrict__ b_hh,   // [H]
    const float* __restrict__ W_ph,   // [O, H]
    const float* __restrict__ b_ph,   // [O]
    float* __restrict__ out)          // [B, O]
{
    const int b    = blockIdx.x;
    const int tid  = threadIdx.x;
    const int j    = tid & (H_DIM - 1);
    const int half = tid >> 7;        // wave-uniform (waves 0,1 -> 0; waves 2,3 -> 1)

    __shared__ float v[KTOT];         // v[0:128] = h, v[128:192] = x_t
    __shared__ float partial[H_DIM];

    // Preload this thread's weight slice: rows of W_cat = [W_hh | W_hx].
    // half 0: W_hh[j, 0:96); half 1: W_hh[j, 96:128) ++ W_hx[j, 0:64).
    float w[WPT];
    #pragma unroll
    for (int m = 0; m < WPT; ++m) {
        const int k = half * WPT + m;
        w[m] = (k < H_DIM) ? W_hh[j * H_DIM + k]
                           : W_hx[j * I_DIM + (k - H_DIM)];
    }
    const float bias = b_hh[j];

    if (tid < H_DIM) v[tid] = 0.0f;   // h0 = 0

    const float* xb = x + (size_t)b * T_STEPS * I_DIM;

    for (int t = 0; t < T_STEPS; ++t) {
        // Stage x_t into v[128:192) (256 B, coalesced single-dword loads).
        if (tid < I_DIM) v[H_DIM + tid] = xb[t * I_DIM + tid];
        __syncthreads();  // h (prev step) + x_t visible to all

        // 96-MAC partial dot: weights in VGPRs, operands via LDS broadcast.
        float acc = 0.0f;
        const float* vp = &v[half * WPT];   // 384B-aligned -> ds_read_b128
        #pragma unroll
        for (int m = 0; m < WPT; ++m) acc += w[m] * vp[m];

        if (half == 1) partial[j] = acc;
        __syncthreads();  // partials visible; also fences v reads before rewrite

        if (half == 0) {
            const float s = acc + partial[j] + bias;
            v[j] = tanhf(s);
        }
        // next iteration's first __syncthreads() orders v[j] writes vs. reads
    }
    __syncthreads();

    // Epilogue: out[b, :] = W_ph @ h + b_ph (tiny: 10x128, once per block).
    if (tid < O_DIM) {
        float acc = b_ph[tid];
        #pragma unroll 4
        for (int k = 0; k < H_DIM; ++k) acc += W_ph[tid * H_DIM + k] * v[k];
        out[b * O_DIM + tid] = acc;
    }
}

extern "C" void kernel_launch(void* const* d_in, const int* in_sizes, int n_in,
                              void* d_out, int out_size, void* d_ws, size_t ws_size,
                              hipStream_t stream) {
    const float* x    = (const float*)d_in[0];
    const float* W_hx = (const float*)d_in[1];
    const float* W_hh = (const float*)d_in[2];
    const float* b_hh = (const float*)d_in[3];
    const float* W_ph = (const float*)d_in[4];
    const float* b_ph = (const float*)d_in[5];
    float* out = (float*)d_out;

    const int B = 1024;
    rnn_fused_kernel<<<B, 256, 0, stream>>>(x, W_hx, W_hh, b_hh, W_ph, b_ph, out);
}